// Round 6
// baseline (114.527 us; speedup 1.0000x reference)
//
#include <hip/hip_runtime.h>

#if defined(__has_builtin)
#  if __has_builtin(__builtin_amdgcn_exp2f)
#    define EXP2F(x) __builtin_amdgcn_exp2f(x)
#  else
#    define EXP2F(x) exp2f(x)
#  endif
#else
#  define EXP2F(x) exp2f(x)
#endif

constexpr int NPIX  = 262144;
constexpr int NC    = 1024;
constexpr int NG    = 256;
constexpr int BLOCK = 256;
constexpr int PIX_PER_BLOCK = 256;   // PPT=1: one pixel per thread, 1024 blocks

// ---- 16-lane butterfly sum on the VALU pipe (DPP), zero ds ops ----
template <int CTRL>
__device__ __forceinline__ float dpp_add(float v) {
    union { float f; int i; } u, t;
    u.f = v;
    t.i = __builtin_amdgcn_update_dpp(0, u.i, CTRL, 0xF, 0xF, true);
    return v + t.f;
}
__device__ __forceinline__ float sum16(float v) {
    v = dpp_add<0xB1>(v);   // quad_perm xor1
    v = dpp_add<0x4E>(v);   // quad_perm xor2
    v = dpp_add<0x141>(v);  // row_half_mirror (xor4 for sums)
    v = dpp_add<0x140>(v);  // row_mirror      (xor8 for sums)
    return v;               // all 16 lanes hold the group total
}

// prep: cpack[c] = (cx, cy, alpha * 2^{f*|c|^2}, 0) in d_ws (16 KB)
__global__ void prep_centers(const float* __restrict__ alphas,
                             const float* __restrict__ centers,
                             const float* __restrict__ sdp2p,
                             float4* __restrict__ cpk)
{
    const int c = blockIdx.x * blockDim.x + threadIdx.x;
    if (c < NC) {
        const float f  = -1.44269504088896340736f / (2.0f * sdp2p[0]);
        const float cx = centers[2 * c + 0];
        const float cy = centers[2 * c + 1];
        cpk[c] = make_float4(cx, cy, alphas[c] * EXP2F(f * (cx * cx + cy * cy)), 0.f);
    }
}

__global__ __launch_bounds__(BLOCK, 4)   // cap VGPR<=128 -> 4 waves/SIMD
void kbpa_main(const float* __restrict__ betas,
               const float* __restrict__ K,
               const float* __restrict__ pixels,
               const float* __restrict__ sdp2p,
               const float4* __restrict__ cpk,
               float* __restrict__ out)
{
    const int tid  = threadIdx.x;
    const int lane = tid & 63;
    const int wave = tid >> 6;
    const int l4   = lane & 15;        // column-slot within a row's 16-lane team
    const int lg   = lane >> 4;        // row sub-index within a 4-row iteration
    const int own  = l4 * 4 + lg;      // owned row within this wave's 64-row group

    const float f   = -1.44269504088896340736f / (2.0f * sdp2p[0]);
    const float m2f = -2.0f * f;

    // betas fragments: lane covers cols 4*l4..+3 of each 64-col quarter
    const float4* bf4 = (const float4*)betas;
    float4 b0[4], b1[4];
    #pragma unroll
    for (int k = 0; k < 4; ++k) {
        b0[k] = bf4[l4 * 2 + k * 32];
        b1[k] = bf4[l4 * 2 + k * 32 + 1];
    }

    const int g0 = blockIdx.x * PIX_PER_BLOCK + wave * 64;
    const float2 mypix = ((const float2*)pixels)[g0 + own];

    // ---- stage A: wave-cooperative deformed coords, DPP reduction ----
    float dx = 0.f, dy = 0.f;
    #pragma unroll 2
    for (int it = 0; it < 16; ++it) {
        const float4* kr = (const float4*)(K + (size_t)(g0 + it * 4 + lg) * NG);
        float4 kv[4];
        #pragma unroll
        for (int k = 0; k < 4; ++k) kv[k] = kr[l4 + 16 * k];
        float sx = 0.f, sy = 0.f;
        #pragma unroll
        for (int k = 0; k < 4; ++k) {
            sx = fmaf(kv[k].x, b0[k].x, sx); sy = fmaf(kv[k].x, b0[k].y, sy);
            sx = fmaf(kv[k].y, b0[k].z, sx); sy = fmaf(kv[k].y, b0[k].w, sy);
            sx = fmaf(kv[k].z, b1[k].x, sx); sy = fmaf(kv[k].z, b1[k].y, sy);
            sx = fmaf(kv[k].w, b1[k].z, sx); sy = fmaf(kv[k].w, b1[k].w, sy);
        }
        sx = sum16(sx); sy = sum16(sy);
        if (l4 == it) { dx = mypix.x - sx; dy = mypix.y - sy; }
    }

    // ---- stage B: 1024 centers, wave-uniform loads, 4 rotating accs ----
    const float dxs = m2f * dx, dys = m2f * dy;
    const float pn  = f * (dx * dx + dy * dy);
    float a0 = 0.f, a1 = 0.f, a2 = 0.f, a3 = 0.f;
    for (int c = 0; c < NC; c += 8) {
        const float4 q0 = cpk[c + 0];
        const float4 q1 = cpk[c + 1];
        const float4 q2 = cpk[c + 2];
        const float4 q3 = cpk[c + 3];
        const float4 q4 = cpk[c + 4];
        const float4 q5 = cpk[c + 5];
        const float4 q6 = cpk[c + 6];
        const float4 q7 = cpk[c + 7];
        a0 = fmaf(q0.z, EXP2F(fmaf(dxs, q0.x, dys * q0.y)), a0);
        a1 = fmaf(q1.z, EXP2F(fmaf(dxs, q1.x, dys * q1.y)), a1);
        a2 = fmaf(q2.z, EXP2F(fmaf(dxs, q2.x, dys * q2.y)), a2);
        a3 = fmaf(q3.z, EXP2F(fmaf(dxs, q3.x, dys * q3.y)), a3);
        a0 = fmaf(q4.z, EXP2F(fmaf(dxs, q4.x, dys * q4.y)), a0);
        a1 = fmaf(q5.z, EXP2F(fmaf(dxs, q5.x, dys * q5.y)), a1);
        a2 = fmaf(q6.z, EXP2F(fmaf(dxs, q6.x, dys * q6.y)), a2);
        a3 = fmaf(q7.z, EXP2F(fmaf(dxs, q7.x, dys * q7.y)), a3);
    }
    out[g0 + own] = ((a0 + a1) + (a2 + a3)) * EXP2F(pn);
}

extern "C" void kernel_launch(void* const* d_in, const int* in_sizes, int n_in,
                              void* d_out, int out_size, void* d_ws, size_t ws_size,
                              hipStream_t stream)
{
    const float* alphas  = (const float*)d_in[0];
    const float* betas   = (const float*)d_in[1];
    const float* K       = (const float*)d_in[2];
    const float* pixels  = (const float*)d_in[3];
    const float* centers = (const float*)d_in[4];
    const float* sdp2    = (const float*)d_in[5];
    float* outp          = (float*)d_out;
    float4* cpk          = (float4*)d_ws;

    hipLaunchKernelGGL(prep_centers, dim3(NC / 256), dim3(256), 0, stream,
                       alphas, centers, sdp2, cpk);
    hipLaunchKernelGGL(kbpa_main, dim3(NPIX / PIX_PER_BLOCK), dim3(BLOCK), 0, stream,
                       betas, K, pixels, sdp2, cpk, outp);
}

// Round 7
// 81.547 us; speedup vs baseline: 1.4044x; 1.4044x over previous
//
#include <hip/hip_runtime.h>

#if defined(__has_builtin)
#  if __has_builtin(__builtin_amdgcn_exp2f)
#    define EXP2F(x) __builtin_amdgcn_exp2f(x)
#  else
#    define EXP2F(x) exp2f(x)
#  endif
#else
#  define EXP2F(x) exp2f(x)
#endif

constexpr int NPIX  = 262144;
constexpr int NC    = 1024;
constexpr int NG    = 256;
constexpr int BLOCK = 256;
constexpr int PIX_PER_BLOCK = 256;   // PPT=1, 1024 blocks -> 4 waves/SIMD resident

// ---- DPP helpers (VALU pipe, no lgkm) ----
template <int CTRL>
__device__ __forceinline__ float dpp_add(float v) {
    union { float f; int i; } u, t;
    u.f = v;
    t.i = __builtin_amdgcn_update_dpp(0, u.i, CTRL, 0xF, 0xF, true);
    return v + t.f;
}
template <int CTRL>
__device__ __forceinline__ float dpp_mov(float v) {
    union { float f; int i; } u, t;
    u.f = v;
    t.i = __builtin_amdgcn_update_dpp(0, u.i, CTRL, 0xF, 0xF, true);
    return t.f;
}
__device__ __forceinline__ float sum16(float v) {
    v = dpp_add<0xB1>(v);   // quad_perm xor1
    v = dpp_add<0x4E>(v);   // quad_perm xor2
    v = dpp_add<0x141>(v);  // row_half_mirror (xor4 for sums)
    v = dpp_add<0x140>(v);  // row_mirror      (xor8 for sums)
    return v;               // all 16 lanes hold the group total
}

// prep: SoA in d_ws: cx[NC] | cy[NC] | ca[NC]  (ca = alpha * 2^{f|c|^2})
__global__ void prep_centers(const float* __restrict__ alphas,
                             const float* __restrict__ centers,
                             const float* __restrict__ sdp2p,
                             float* __restrict__ ws)
{
    const int c = blockIdx.x * blockDim.x + threadIdx.x;
    if (c < NC) {
        const float f  = -1.44269504088896340736f / (2.0f * sdp2p[0]);
        const float cx = centers[2 * c + 0];
        const float cy = centers[2 * c + 1];
        ws[c]          = cx;
        ws[NC + c]     = cy;
        ws[2 * NC + c] = alphas[c] * EXP2F(f * (cx * cx + cy * cy));
    }
}

__global__ __launch_bounds__(BLOCK, 4)   // cap VGPR<=128 -> 4 waves/SIMD
void kbpa_main(const float* __restrict__ betas,
               const float* __restrict__ K,
               const float* __restrict__ pixels,
               const float* __restrict__ sdp2p,
               const float* __restrict__ ws,
               float* __restrict__ out)
{
    const int tid  = threadIdx.x;
    const int lane = tid & 63;
    const int wave = tid >> 6;
    const int l4   = lane & 15;        // column-slot within a row's 16-lane team
    const int lg   = lane >> 4;        // row sub-index within a 4-row iteration
    const int own  = l4 * 4 + lg;      // owned pixel row within the wave's 64

    const float f   = -1.44269504088896340736f / (2.0f * sdp2p[0]);
    const float m2f = -2.0f * f;

    // register-resident centers: lane holds c = lane*16 .. lane*16+15 (SoA)
    const float4* wcx4 = (const float4*)(ws);
    const float4* wcy4 = (const float4*)(ws + NC);
    const float4* wca4 = (const float4*)(ws + 2 * NC);
    float4 rcx[4], rcy[4], rca[4];
    #pragma unroll
    for (int j = 0; j < 4; ++j) {
        rcx[j] = wcx4[lane * 4 + j];
        rcy[j] = wcy4[lane * 4 + j];
        rca[j] = wca4[lane * 4 + j];
    }

    // betas fragments: lane covers cols 4*l4..+3 of each 64-col quarter
    const float4* bf4 = (const float4*)betas;
    float4 b0[4], b1[4];
    #pragma unroll
    for (int k = 0; k < 4; ++k) {
        b0[k] = bf4[l4 * 2 + k * 32];
        b1[k] = bf4[l4 * 2 + k * 32 + 1];
    }

    const int g0 = blockIdx.x * PIX_PER_BLOCK + wave * 64;
    const float2 mypix = ((const float2*)pixels)[g0 + own];

    // ---- stage A: wave-cooperative deformed coords, DPP reduction ----
    float dx = 0.f, dy = 0.f;
    #pragma unroll 2
    for (int it = 0; it < 16; ++it) {
        const float4* kr = (const float4*)(K + (size_t)(g0 + it * 4 + lg) * NG);
        float4 kv[4];
        #pragma unroll
        for (int k = 0; k < 4; ++k) kv[k] = kr[l4 + 16 * k];
        float sx = 0.f, sy = 0.f;
        #pragma unroll
        for (int k = 0; k < 4; ++k) {
            sx = fmaf(kv[k].x, b0[k].x, sx); sy = fmaf(kv[k].x, b0[k].y, sy);
            sx = fmaf(kv[k].y, b0[k].z, sx); sy = fmaf(kv[k].y, b0[k].w, sy);
            sx = fmaf(kv[k].z, b1[k].x, sx); sy = fmaf(kv[k].z, b1[k].y, sy);
            sx = fmaf(kv[k].w, b1[k].z, sx); sy = fmaf(kv[k].w, b1[k].w, sy);
        }
        sx = sum16(sx); sy = sum16(sy);
        if (l4 == it) { dx = mypix.x - sx; dy = mypix.y - sy; }
    }

    // ---- stage B: DPP-systolic over register-resident centers ----
    // state (dxs, dys, acc) rotates: row_ror:1 within 16-lane rows (DPP,
    // VALU pipe), row swaps ^16/^32 at round boundaries (only 12 bpermutes).
    float dxs = m2f * dx, dys = m2f * dy, acc = 0.f;
    #pragma unroll 1
    for (int round = 0; round < 4; ++round) {
        #pragma unroll 2
        for (int t = 0; t < 16; ++t) {
            float t0 = 0.f, t1 = 0.f, t2 = 0.f, t3 = 0.f;
            #pragma unroll
            for (int j = 0; j < 4; ++j) {
                t0 = fmaf(rca[j].x, EXP2F(fmaf(dxs, rcx[j].x, dys * rcy[j].x)), t0);
                t1 = fmaf(rca[j].y, EXP2F(fmaf(dxs, rcx[j].y, dys * rcy[j].y)), t1);
                t2 = fmaf(rca[j].z, EXP2F(fmaf(dxs, rcx[j].z, dys * rcy[j].z)), t2);
                t3 = fmaf(rca[j].w, EXP2F(fmaf(dxs, rcx[j].w, dys * rcy[j].w)), t3);
            }
            acc += (t0 + t1) + (t2 + t3);
            dxs = dpp_mov<0x121>(dxs);   // row_ror:1
            dys = dpp_mov<0x121>(dys);
            acc = dpp_mov<0x121>(acc);
        }
        const int sw = lane ^ ((round & 1) ? 32 : 16);  // ^16,^32,^16,^32 -> home
        dxs = __shfl(dxs, sw);
        dys = __shfl(dys, sw);
        acc = __shfl(acc, sw);
    }

    out[g0 + own] = acc * EXP2F(f * (dx * dx + dy * dy));
}

extern "C" void kernel_launch(void* const* d_in, const int* in_sizes, int n_in,
                              void* d_out, int out_size, void* d_ws, size_t ws_size,
                              hipStream_t stream)
{
    const float* alphas  = (const float*)d_in[0];
    const float* betas   = (const float*)d_in[1];
    const float* K       = (const float*)d_in[2];
    const float* pixels  = (const float*)d_in[3];
    const float* centers = (const float*)d_in[4];
    const float* sdp2    = (const float*)d_in[5];
    float* outp          = (float*)d_out;
    float* ws            = (float*)d_ws;

    hipLaunchKernelGGL(prep_centers, dim3(NC / 256), dim3(256), 0, stream,
                       alphas, centers, sdp2, ws);
    hipLaunchKernelGGL(kbpa_main, dim3(NPIX / PIX_PER_BLOCK), dim3(BLOCK), 0, stream,
                       betas, K, pixels, sdp2, ws, outp);
}